// Round 1
// baseline (146.972 us; speedup 1.0000x reference)
//
#include <hip/hip_runtime.h>
#include <math.h>

// Problem constants (reference: B,F,W,H,D = 128,1024,32,64,64)
#define B_   128
#define F_   1024
#define W_   32
#define H_   64
#define K4H  256   // 4*H

// ---------------------------------------------------------------------------
// Phase 1: G[m, k] = sum_f x[b, f, t] * Wx[f, k],   m = b*W_ + t
// (the attention softmax over a size-1 axis is identically 1, so the gate
//  input projection is h-independent and hoisted out of the recurrence)
// Tiled fp32 GEMM: M=4096, N=256, K=1024. grid (64,4), 256 threads,
// 64x64 output tile per block, 4x4 accumulators per thread.
// ---------------------------------------------------------------------------
__global__ __launch_bounds__(256) void gates_gemm(
    const float* __restrict__ x,   // [B, F, W]
    const float* __restrict__ Wx,  // [F, 4H]
    float* __restrict__ G) {       // [B*W, 4H]
  __shared__ float As[32][64];  // [f_local][m_local]  (x transposed tile)
  __shared__ float Bs[32][64];  // [f_local][n_local]

  const int tid   = threadIdx.x;
  const int tm    = tid & 15;   // 0..15 -> 4 m's each
  const int tn    = tid >> 4;   // 0..15 -> 4 k's each
  const int mtile = blockIdx.x; // 0..63 (64 m's = 2 batch elements)
  const int ntile = blockIdx.y; // 0..3  (64 k's)
  const int b0    = mtile * 2;

  float acc[4][4];
#pragma unroll
  for (int i = 0; i < 4; ++i)
#pragma unroll
    for (int j = 0; j < 4; ++j) acc[i][j] = 0.f;

  for (int f0 = 0; f0 < F_; f0 += 32) {
    // A tile: x[b0+bl, f0+fl, t0..t0+3] -> As[fl][bl*32 + t0..t0+3]
#pragma unroll
    for (int i = 0; i < 2; ++i) {
      int l  = tid + i * 256;        // 0..511 float4's
      int t0 = (l & 7) * 4;
      int fl = (l >> 3) & 31;
      int bl = l >> 8;
      float4 v = *(const float4*)&x[(((size_t)(b0 + bl)) * F_ + (f0 + fl)) * W_ + t0];
      *(float4*)&As[fl][bl * 32 + t0] = v;
    }
    // B tile: Wx[f0+fl, ntile*64 + n0..n0+3] -> Bs[fl][n0..n0+3]
#pragma unroll
    for (int i = 0; i < 2; ++i) {
      int l  = tid + i * 256;
      int n0 = (l & 15) * 4;
      int fl = l >> 4;
      float4 v = *(const float4*)&Wx[(size_t)(f0 + fl) * K4H + ntile * 64 + n0];
      *(float4*)&Bs[fl][n0] = v;
    }
    __syncthreads();

#pragma unroll
    for (int f = 0; f < 32; ++f) {
      float4 a4 = *(const float4*)&As[f][tm * 4];
      float4 b4 = *(const float4*)&Bs[f][tn * 4];
      float av[4] = {a4.x, a4.y, a4.z, a4.w};
      float bv[4] = {b4.x, b4.y, b4.z, b4.w};
#pragma unroll
      for (int i = 0; i < 4; ++i)
#pragma unroll
        for (int j = 0; j < 4; ++j)
          acc[i][j] = fmaf(av[i], bv[j], acc[i][j]);
    }
    __syncthreads();
  }

#pragma unroll
  for (int i = 0; i < 4; ++i) {
    int m = mtile * 64 + tm * 4 + i;
    int k = ntile * 64 + tn * 4;
    float4 v = make_float4(acc[i][0], acc[i][1], acc[i][2], acc[i][3]);
    *(float4*)&G[(size_t)m * K4H + k] = v;
  }
}

// ---------------------------------------------------------------------------
// Phase 2: sequential LSTM, one block per batch element.
// Thread k in [0,256) owns gate lane k. Wh column k lives in 64 registers.
// Gate order (Keras): i = [0,64), f = [64,128), g = [128,192), o = [192,256).
// c_new = sig(f)*c + sig(i)*tanh(g); h_new = sig(o)*tanh(c_new).
// Output (due to the reference's s,h swap) is the CELL state sequence.
// Wave-uniform activation branch: k in [128,192) is exactly wave 2.
// ---------------------------------------------------------------------------
__device__ __forceinline__ float fast_sigmoid(float v) {
  return 1.f / (1.f + __expf(-v));
}
__device__ __forceinline__ float fast_tanh(float v) {
  return 1.f - 2.f / (__expf(2.f * v) + 1.f);
}

__global__ __launch_bounds__(256) void lstm_seq(
    const float* __restrict__ G,     // [B, W, 4H]
    const float* __restrict__ Wh,    // [H, 4H]
    const float* __restrict__ bl,    // [4H]
    float* __restrict__ out) {       // [B, W, H]
  __shared__ float sh[H_];    // hidden state h_t
  __shared__ float sact[K4H]; // activated gates

  const int b = blockIdx.x;
  const int k = threadIdx.x;

  // Wh column k -> registers (coalesced across threads; Wh is 64 KB, L2-hot)
  float wcol[H_];
#pragma unroll
  for (int j = 0; j < H_; ++j) wcol[j] = Wh[j * K4H + k];
  const float bias = bl[k];

  float c = 0.f;
  if (k < H_) sh[k] = 0.f;
  __syncthreads();

  const float* Gb = G + (size_t)b * W_ * K4H;
  float* outb = out + (size_t)b * W_ * H_;

  for (int t = 0; t < W_; ++t) {
    float g = Gb[t * K4H + k] + bias;
#pragma unroll
    for (int j = 0; j < H_; ++j) g = fmaf(sh[j], wcol[j], g);

    float act;
    if (k < 2 * H_ || k >= 3 * H_) {
      act = fast_sigmoid(g);   // i, f, o  (waves 0,1,3)
    } else {
      act = fast_tanh(g);      // g        (wave 2)
    }
    sact[k] = act;
    __syncthreads();

    if (k < H_) {
      float ig = sact[k];
      float fg = sact[H_ + k];
      float gg = sact[2 * H_ + k];
      float og = sact[3 * H_ + k];
      c = fg * c + ig * gg;
      sh[k] = og * fast_tanh(c);
      outb[t * H_ + k] = c;    // reference returns the cell state
    }
    __syncthreads();
  }
}

// ---------------------------------------------------------------------------
extern "C" void kernel_launch(void* const* d_in, const int* in_sizes, int n_in,
                              void* d_out, int out_size, void* d_ws, size_t ws_size,
                              hipStream_t stream) {
  // setup_inputs order:
  // 0:x 1:W_state 2:b_state 3:W_in 4:w_attn 5:b_attn 6:Wx 7:Wh 8:b_lstm
  const float* x      = (const float*)d_in[0];
  const float* Wx     = (const float*)d_in[6];
  const float* Wh     = (const float*)d_in[7];
  const float* b_lstm = (const float*)d_in[8];
  float* out = (float*)d_out;
  float* G   = (float*)d_ws;  // [B*W, 4H] = 4 MB fp32 scratch

  dim3 g1(64, 4);
  gates_gemm<<<g1, dim3(256), 0, stream>>>(x, Wx, G);
  lstm_seq<<<dim3(B_), dim3(256), 0, stream>>>(G, Wh, b_lstm, out);
}